// Round 1
// baseline (3897.990 us; speedup 1.0000x reference)
//
#include <hip/hip_runtime.h>

#define H 100
#define L 3

// One thread per row. Weights for the current (layer, potential) staged in LDS:
//   sW1b[k] = (W1[k][0], W1[k][1], W1[k][2], b1[k])   packed float4
//   sW2[j*H+k]                                         row-major, ds_read_b128-able
//   sb2w3[j] = (b2[j], w3[j])
// All weight reads are wave-uniform -> LDS broadcast (conflict-free).
// s1[] and g1[] live in registers (only constant-indexed in unrolled loops).
// __launch_bounds__(256,2): ~230 VGPR target -> 2 waves/SIMD, 2 blocks/CU.
__global__ __launch_bounds__(256, 2) void sympnet_kernel(
    const float* __restrict__ z,   const float* __restrict__ t,
    const float* __restrict__ Wq1, const float* __restrict__ bq1,
    const float* __restrict__ Wq2, const float* __restrict__ bq2,
    const float* __restrict__ wq3,
    const float* __restrict__ Wp1, const float* __restrict__ bp1,
    const float* __restrict__ Wp2, const float* __restrict__ bp2,
    const float* __restrict__ wp3,
    float* __restrict__ out)
{
    __shared__ float4 sW1b[H];
    __shared__ float2 sb2w3[H];
    __shared__ float  sW2[H * H];

    const int tid = threadIdx.x;
    const int r   = blockIdx.x * 256 + tid;

    const float4 zr = reinterpret_cast<const float4*>(z)[r];
    float q0 = zr.x, q1 = zr.y, p0 = zr.z, p1 = zr.w;
    const float tval = t[r];

    #pragma unroll 1
    for (int layer = 0; layer < L; ++layer) {
      #pragma unroll 1
      for (int pot = 0; pot < 2; ++pot) {
        // ---- stage weights for this (layer, pot) into LDS ----
        __syncthreads();  // all waves done with previous weights
        {
          const float* gW2 = (pot ? Wp2 : Wq2) + layer * (H * H);
          const float4* gW2v = reinterpret_cast<const float4*>(gW2);
          float4* sW2v = reinterpret_cast<float4*>(sW2);
          #pragma unroll 1
          for (int idx = tid; idx < (H * H) / 4; idx += 256)
            sW2v[idx] = gW2v[idx];
          if (tid < H) {
            const float* gW1 = (pot ? Wp1 : Wq1) + layer * (H * 3);
            const float* gb1 = (pot ? bp1 : bq1) + layer * H;
            const float* gb2 = (pot ? bp2 : bq2) + layer * H;
            const float* gw3 = (pot ? wp3 : wq3) + layer * H;
            sW1b[tid]  = make_float4(gW1[tid * 3], gW1[tid * 3 + 1],
                                     gW1[tid * 3 + 2], gb1[tid]);
            sb2w3[tid] = make_float2(gb2[tid], gw3[tid]);
          }
        }
        __syncthreads();

        const float x0 = pot ? p0 : q0;
        const float x1 = pot ? p1 : q1;
        float d0 = 0.f, d1 = 0.f;

        #pragma unroll 1
        for (int e = 0; e < 2; ++e) {
          const float xt = e ? 0.f : tval;

          // ---- stage 1: s1 = sin(W1 @ [x;t] + b1) ----
          float s1[H];
          #pragma unroll
          for (int k = 0; k < H; ++k) {
            float4 w = sW1b[k];
            float h = __builtin_fmaf(w.x, x0,
                      __builtin_fmaf(w.y, x1,
                      __builtin_fmaf(w.z, xt, w.w)));
            s1[k] = __sinf(h);
          }

          float g1[H];
          #pragma unroll
          for (int k = 0; k < H; ++k) g1[k] = 0.f;

          // ---- fused stage 2+3: per hidden unit j ----
          #pragma unroll 1
          for (int j = 0; j < H; ++j) {
            const float* row = &sW2[j * H];
            float h2a = 0.f, h2b = 0.f, h2c = 0.f, h2d = 0.f;
            #pragma unroll
            for (int k = 0; k < H; k += 4) {
              h2a = __builtin_fmaf(row[k + 0], s1[k + 0], h2a);
              h2b = __builtin_fmaf(row[k + 1], s1[k + 1], h2b);
              h2c = __builtin_fmaf(row[k + 2], s1[k + 2], h2c);
              h2d = __builtin_fmaf(row[k + 3], s1[k + 3], h2d);
            }
            const float2 bw = sb2w3[j];
            const float g2 = __cosf(((h2a + h2b) + (h2c + h2d)) + bw.x) * bw.y;
            #pragma unroll
            for (int k = 0; k < H; ++k)
              g1[k] = __builtin_fmaf(g2, row[k], g1[k]);
          }

          // ---- output: (g1 * cos(h1)) @ W1, first two columns ----
          float a0 = 0.f, a1 = 0.f, a2 = 0.f, a3 = 0.f;
          #pragma unroll
          for (int k = 0; k < H; k += 2) {
            float4 wA = sW1b[k], wB = sW1b[k + 1];
            float hA = __builtin_fmaf(wA.x, x0,
                       __builtin_fmaf(wA.y, x1,
                       __builtin_fmaf(wA.z, xt, wA.w)));
            float hB = __builtin_fmaf(wB.x, x0,
                       __builtin_fmaf(wB.y, x1,
                       __builtin_fmaf(wB.z, xt, wB.w)));
            float gA = g1[k] * __cosf(hA);
            float gB = g1[k + 1] * __cosf(hB);
            a0 = __builtin_fmaf(gA, wA.x, a0);
            a1 = __builtin_fmaf(gA, wA.y, a1);
            a2 = __builtin_fmaf(gB, wB.x, a2);
            a3 = __builtin_fmaf(gB, wB.y, a3);
          }
          const float sg = e ? -1.f : 1.f;
          d0 = __builtin_fmaf(sg, a0 + a2, d0);
          d1 = __builtin_fmaf(sg, a1 + a3, d1);
        }

        if (pot == 0) { p0 -= d0; p1 -= d1; }
        else          { q0 += d0; q1 += d1; }
      }
    }

    float4 o;
    o.x = q0; o.y = q1; o.z = p0; o.w = p1;
    reinterpret_cast<float4*>(out)[r] = o;
}

extern "C" void kernel_launch(void* const* d_in, const int* in_sizes, int n_in,
                              void* d_out, int out_size, void* d_ws, size_t ws_size,
                              hipStream_t stream) {
    const float* z   = (const float*)d_in[0];
    const float* t   = (const float*)d_in[1];
    const float* Wq1 = (const float*)d_in[2];
    const float* bq1 = (const float*)d_in[3];
    const float* Wq2 = (const float*)d_in[4];
    const float* bq2 = (const float*)d_in[5];
    const float* wq3 = (const float*)d_in[6];
    const float* Wp1 = (const float*)d_in[7];
    const float* bp1 = (const float*)d_in[8];
    const float* Wp2 = (const float*)d_in[9];
    const float* bp2 = (const float*)d_in[10];
    const float* wp3 = (const float*)d_in[11];
    float* out = (float*)d_out;

    const int B = in_sizes[1];        // 131072 rows (t has one per row)
    const int blocks = B / 256;       // 512 blocks, exact

    sympnet_kernel<<<blocks, 256, 0, stream>>>(
        z, t, Wq1, bq1, Wq2, bq2, wq3, Wp1, bp1, Wp2, bp2, wp3, out);
}

// Round 2
// 2222.129 us; speedup vs baseline: 1.7542x; 1.7542x over previous
//
#include <hip/hip_runtime.h>

#define H  100
#define HP 112            // padded hidden dim = 4 lanes * 28
#define PL 28             // hidden elements per lane
#define PV 7              // float4 chunks per lane
#define L  3

// quad_perm DPP lane swaps (full-rate VALU, no LDS pipe)
__device__ __forceinline__ float dpp_xor1(float x) {   // lane ^ 1: [1,0,3,2] = 0xB1
    return __int_as_float(__builtin_amdgcn_update_dpp(
        0, __float_as_int(x), 0xB1, 0xF, 0xF, true));
}
__device__ __forceinline__ float dpp_xor2(float x) {   // lane ^ 2: [2,3,0,1] = 0x4E
    return __int_as_float(__builtin_amdgcn_update_dpp(
        0, __float_as_int(x), 0x4E, 0xF, 0xF, true));
}
__device__ __forceinline__ float quad_sum(float x) {
    x += dpp_xor1(x);
    x += dpp_xor2(x);
    return x;
}

// 4 lanes (a quad) cooperate on one row. Each lane owns 28 of the 112
// (padded) hidden units. Live set per lane: s1[28]+g1[28]+row[28] ~ 110 VGPR.
// Weights in LDS; all reads are 4-distinct-address broadcasts (conflict-free).
__global__ __launch_bounds__(256, 4) void sympnet_kernel(
    const float* __restrict__ z,   const float* __restrict__ t,
    const float* __restrict__ Wq1, const float* __restrict__ bq1,
    const float* __restrict__ Wq2, const float* __restrict__ bq2,
    const float* __restrict__ wq3,
    const float* __restrict__ Wp1, const float* __restrict__ bp1,
    const float* __restrict__ Wp2, const float* __restrict__ bp2,
    const float* __restrict__ wp3,
    float* __restrict__ out)
{
    __shared__ float4 sW2[H * PV * 4];   // row j = sW2[j*28 .. j*28+27], 112 floats (padded)
    __shared__ float4 sW1b[HP];          // (W1[k][0..2], b1[k]), zero-padded k>=100
    __shared__ float2 sb2w3[H];          // (b2[j], w3[j])

    const int tid   = threadIdx.x;
    const int s     = tid & 3;           // sub-lane within quad
    const int r     = blockIdx.x * 64 + (tid >> 2);
    const int kbase = s * PL;

    const float4 zr = reinterpret_cast<const float4*>(z)[r];
    float q0 = zr.x, q1 = zr.y, p0 = zr.z, p1 = zr.w;
    const float tval = t[r];

    #pragma unroll 1
    for (int layer = 0; layer < L; ++layer) {
      #pragma unroll 1
      for (int pot = 0; pot < 2; ++pot) {
        // ---- stage weights for this (layer, pot) into LDS ----
        __syncthreads();
        {
          const float*  gW2  = (pot ? Wp2 : Wq2) + layer * (H * H);
          const float4* gW2v = reinterpret_cast<const float4*>(gW2);  // 25 float4 per row
          #pragma unroll 1
          for (int idx = tid; idx < H * 28; idx += 256) {
            const int j = idx / 28;
            const int c = idx - j * 28;
            sW2[j * 28 + c] = (c < 25) ? gW2v[j * 25 + c]
                                       : make_float4(0.f, 0.f, 0.f, 0.f);
          }
          if (tid < HP) {
            float4 w = make_float4(0.f, 0.f, 0.f, 0.f);
            if (tid < H) {
              const float* gW1 = (pot ? Wp1 : Wq1) + layer * (H * 3);
              const float* gb1 = (pot ? bp1 : bq1) + layer * H;
              w = make_float4(gW1[tid * 3], gW1[tid * 3 + 1],
                              gW1[tid * 3 + 2], gb1[tid]);
            }
            sW1b[tid] = w;
          }
          if (tid < H) {
            const float* gb2 = (pot ? bp2 : bq2) + layer * H;
            const float* gw3 = (pot ? wp3 : wq3) + layer * H;
            sb2w3[tid] = make_float2(gb2[tid], gw3[tid]);
          }
        }
        __syncthreads();

        const float x0 = pot ? p0 : q0;
        const float x1 = pot ? p1 : q1;
        float d0 = 0.f, d1 = 0.f;

        #pragma unroll 1
        for (int e = 0; e < 2; ++e) {
          const float xt = e ? 0.f : tval;

          // ---- stage 1: s1[i] = sin(W1 @ [x;t] + b1), own 28 units ----
          float s1[PL];
          #pragma unroll
          for (int i = 0; i < PL; ++i) {
            const float4 w = sW1b[kbase + i];
            const float h = __builtin_fmaf(w.x, x0,
                            __builtin_fmaf(w.y, x1,
                            __builtin_fmaf(w.z, xt, w.w)));
            s1[i] = __sinf(h);
          }

          float g1[PL];
          #pragma unroll
          for (int i = 0; i < PL; ++i) g1[i] = 0.f;

          // ---- fused stage 2+3 core: loop over hidden units j ----
          #pragma unroll 1
          for (int j = 0; j < H; ++j) {
            const float4* rowp = &sW2[j * 28 + s * PV];
            float4 rw[PV];
            #pragma unroll
            for (int c = 0; c < PV; ++c) rw[c] = rowp[c];

            float ha = 0.f, hb = 0.f, hc = 0.f, hd = 0.f;
            #pragma unroll
            for (int c = 0; c < PV; ++c) {
              ha = __builtin_fmaf(rw[c].x, s1[4 * c + 0], ha);
              hb = __builtin_fmaf(rw[c].y, s1[4 * c + 1], hb);
              hc = __builtin_fmaf(rw[c].z, s1[4 * c + 2], hc);
              hd = __builtin_fmaf(rw[c].w, s1[4 * c + 3], hd);
            }
            const float h2 = quad_sum((ha + hb) + (hc + hd));
            const float2 bw = sb2w3[j];
            const float g2 = __cosf(h2 + bw.x) * bw.y;

            #pragma unroll
            for (int c = 0; c < PV; ++c) {
              g1[4 * c + 0] = __builtin_fmaf(g2, rw[c].x, g1[4 * c + 0]);
              g1[4 * c + 1] = __builtin_fmaf(g2, rw[c].y, g1[4 * c + 1]);
              g1[4 * c + 2] = __builtin_fmaf(g2, rw[c].z, g1[4 * c + 2]);
              g1[4 * c + 3] = __builtin_fmaf(g2, rw[c].w, g1[4 * c + 3]);
            }
          }

          // ---- stage 3: a = (g1 * cos(h1)) @ W1[:, 0:2] ----
          float a0 = 0.f, a1 = 0.f;
          #pragma unroll
          for (int i = 0; i < PL; ++i) {
            const float4 w = sW1b[kbase + i];
            const float h = __builtin_fmaf(w.x, x0,
                            __builtin_fmaf(w.y, x1,
                            __builtin_fmaf(w.z, xt, w.w)));
            const float g = g1[i] * __cosf(h);
            a0 = __builtin_fmaf(g, w.x, a0);
            a1 = __builtin_fmaf(g, w.y, a1);
          }
          a0 = quad_sum(a0);
          a1 = quad_sum(a1);

          const float sg = e ? -1.f : 1.f;
          d0 = __builtin_fmaf(sg, a0, d0);
          d1 = __builtin_fmaf(sg, a1, d1);
        }

        if (pot == 0) { p0 -= d0; p1 -= d1; }
        else          { q0 += d0; q1 += d1; }
      }
    }

    if (s == 0) {
        float4 o;
        o.x = q0; o.y = q1; o.z = p0; o.w = p1;
        reinterpret_cast<float4*>(out)[r] = o;
    }
}

extern "C" void kernel_launch(void* const* d_in, const int* in_sizes, int n_in,
                              void* d_out, int out_size, void* d_ws, size_t ws_size,
                              hipStream_t stream) {
    const float* z   = (const float*)d_in[0];
    const float* t   = (const float*)d_in[1];
    const float* Wq1 = (const float*)d_in[2];
    const float* bq1 = (const float*)d_in[3];
    const float* Wq2 = (const float*)d_in[4];
    const float* bq2 = (const float*)d_in[5];
    const float* wq3 = (const float*)d_in[6];
    const float* Wp1 = (const float*)d_in[7];
    const float* bp1 = (const float*)d_in[8];
    const float* Wp2 = (const float*)d_in[9];
    const float* bp2 = (const float*)d_in[10];
    const float* wp3 = (const float*)d_in[11];
    float* out = (float*)d_out;

    const int B = in_sizes[1];            // 131072 rows
    const int blocks = B / 64;            // 64 rows per block (4 lanes/row), 2048 blocks

    sympnet_kernel<<<blocks, 256, 0, stream>>>(
        z, t, Wq1, bq1, Wq2, bq2, wq3, Wp1, bp1, Wp2, bp2, wp3, out);
}

// Round 4
// 1342.293 us; speedup vs baseline: 2.9040x; 1.6555x over previous
//
#include <hip/hip_runtime.h>
#include <hip/hip_bf16.h>

#define HH 100      // hidden size
#define HP 112      // padded hidden (7*16)
#define MT 7        // 16-wide tiles over hidden
#define KS 120      // row stride (bf16 elems) of LDS W2 buffers
#define RB 128      // rows per block (4 waves * 32 rows)
#define LL 3

typedef __attribute__((ext_vector_type(4))) short bf16x4;
typedef __attribute__((ext_vector_type(4))) float f32x4;

// D = A(16x16) @ B(16x16) + C via v_mfma_f32_16x16x16_bf16 (gfx950, cdna4_isa §10).
// A: lane m=l&15 holds k=(l>>4)*4+i ; B: lane n=l&15 holds k=(l>>4)*4+i ;
// C/D: col=l&15, row=(l>>4)*4+reg.
// Use the intrinsic so the compiler inserts MFMA<->VALU hazard wait-states
// (raw inline asm skipped them -> NaN from undefined register reads, R3).
__device__ __forceinline__ f32x4 mfma16(bf16x4 a, bf16x4 b, f32x4 c) {
#if __has_builtin(__builtin_amdgcn_mfma_f32_16x16x16bf16_1k)
    return __builtin_amdgcn_mfma_f32_16x16x16bf16_1k(a, b, c, 0, 0, 0);
#else
    asm volatile("s_nop 1\n\t"
                 "v_mfma_f32_16x16x16_bf16 %0, %1, %2, %0\n\t"
                 "s_nop 7\n\t"
                 "s_nop 7"
                 : "+v"(c) : "v"(a), "v"(b));
    return c;
#endif
}

__device__ __forceinline__ short f2b(float f) {
    union { __hip_bfloat16 h; short s; } u;
    u.h = __float2bfloat16(f);
    return u.s;
}

__global__ __launch_bounds__(256, 2) void sympnet_kernel(
    const float* __restrict__ z,   const float* __restrict__ t,
    const float* __restrict__ Wq1, const float* __restrict__ bq1,
    const float* __restrict__ Wq2, const float* __restrict__ bq2,
    const float* __restrict__ wq3,
    const float* __restrict__ Wp1, const float* __restrict__ bp1,
    const float* __restrict__ Wp2, const float* __restrict__ bp2,
    const float* __restrict__ wp3,
    float* __restrict__ out)
{
    __shared__ short  sW2b[HP * KS];   // W2[j][k] bf16, zero-padded
    __shared__ short  sW2T[HP * KS];   // W2^T[k'][j] bf16, zero-padded
    __shared__ float4 sW1b[HP];        // (W1[k][0],W1[k][1],W1[k][2],b1[k]), zero-padded
    __shared__ float2 sb2w3[HP];       // (b2[j], w3[j]), zero-padded
    __shared__ float4 sState[RB];      // (q0,q1,p0,p1) per row
    __shared__ float  sT[RB];

    const int tid = threadIdx.x;
    const int m   = tid & 15;          // lane & 15
    const int g   = (tid >> 4) & 3;    // lane-group within wave
    const int waveRow = (tid >> 6) * 32;
    const int gbase   = blockIdx.x * RB;

    if (tid < RB) {
        sState[tid] = reinterpret_cast<const float4*>(z)[gbase + tid];
        sT[tid]     = t[gbase + tid];
    }

    #pragma unroll 1
    for (int layer = 0; layer < LL; ++layer) {
      #pragma unroll 1
      for (int pot = 0; pot < 2; ++pot) {
        const float* gW2 = (pot ? Wp2 : Wq2) + layer * (HH * HH);
        const float* gW1 = (pot ? Wp1 : Wq1) + layer * (HH * 3);
        const float* gb1 = (pot ? bp1 : bq1) + layer * HH;
        const float* gb2 = (pot ? bp2 : bq2) + layer * HH;
        const float* gw3 = (pot ? wp3 : wq3) + layer * HH;

        __syncthreads();   // prior stage done with weight buffers (also covers init)

        // ---- stage sW2b (coalesced) + small weights ----
        #pragma unroll 1
        for (int idx = tid; idx < HP * 30; idx += 256) {
            const int j  = idx / 30;
            const int kc = idx - j * 30;
            bf16x4 v = {0, 0, 0, 0};
            if (j < HH && kc < 25) {
                const float4 w = reinterpret_cast<const float4*>(gW2)[j * 25 + kc];
                v[0] = f2b(w.x); v[1] = f2b(w.y); v[2] = f2b(w.z); v[3] = f2b(w.w);
            }
            *reinterpret_cast<bf16x4*>(&sW2b[j * KS + 4 * kc]) = v;
        }
        if (tid < HP) {
            float4 w  = make_float4(0.f, 0.f, 0.f, 0.f);
            float2 bw = make_float2(0.f, 0.f);
            if (tid < HH) {
                w  = make_float4(gW1[tid * 3], gW1[tid * 3 + 1], gW1[tid * 3 + 2], gb1[tid]);
                bw = make_float2(gb2[tid], gw3[tid]);
            }
            sW1b[tid]  = w;
            sb2w3[tid] = bw;
        }
        __syncthreads();

        // ---- transpose sW2b -> sW2T in LDS ----
        #pragma unroll 1
        for (int idx = tid; idx < HP * 30; idx += 256) {
            const int kp = idx % HP;
            const int jc = idx / HP;        // 0..29
            bf16x4 v;
            #pragma unroll
            for (int i = 0; i < 4; ++i) {
                const int j = 4 * jc + i;
                v[i] = (j < HP) ? sW2b[j * KS + kp] : (short)0;
            }
            *reinterpret_cast<bf16x4*>(&sW2T[kp * KS + 4 * jc]) = v;
        }
        __syncthreads();

        // ---- compute: wave owns 32 rows (two 16-row tiles nt=0,1) ----
        const float4 s0 = sState[waveRow + m];
        const float4 s1 = sState[waveRow + 16 + m];
        const float tr0 = sT[waveRow + m];
        const float tr1 = sT[waveRow + 16 + m];
        const float x00 = pot ? s0.z : s0.x, x01 = pot ? s0.w : s0.y;
        const float x10 = pot ? s1.z : s1.x, x11 = pot ? s1.w : s1.y;

        float dsav00 = 0.f, dsav01 = 0.f, dsav10 = 0.f, dsav11 = 0.f;
        float df00 = 0.f, df01 = 0.f, df10 = 0.f, df11 = 0.f;

        #pragma unroll 1
        for (int e = 0; e < 2; ++e) {
          const float xt0 = e ? 0.f : tr0;
          const float xt1 = e ? 0.f : tr1;

          // H1 (f32 VALU) + sin/cos; sin lands directly in pass-1 B-frag layout
          float  cosr[MT][2][4];
          bf16x4 sf[MT][2];
          #pragma unroll
          for (int mt = 0; mt < MT; ++mt) {
            #pragma unroll
            for (int r = 0; r < 4; ++r) {
              const int k = 16 * mt + 4 * g + r;
              const float4 w = sW1b[k];
              const float h0 = __builtin_fmaf(w.x, x00,
                               __builtin_fmaf(w.y, x01,
                               __builtin_fmaf(w.z, xt0, w.w)));
              const float h1 = __builtin_fmaf(w.x, x10,
                               __builtin_fmaf(w.y, x11,
                               __builtin_fmaf(w.z, xt1, w.w)));
              sf[mt][0][r] = f2b(__sinf(h0));
              sf[mt][1][r] = f2b(__sinf(h1));
              cosr[mt][0][r] = __cosf(h0);
              cosr[mt][1][r] = __cosf(h1);
            }
          }

          // pass 1 (transposed): H2^T[j][row] = W2 @ S1^T
          f32x4 acc[MT][2];
          #pragma unroll
          for (int mt = 0; mt < MT; ++mt) { acc[mt][0] = (f32x4)0.f; acc[mt][1] = (f32x4)0.f; }
          #pragma unroll
          for (int kt = 0; kt < MT; ++kt) {
            #pragma unroll
            for (int mt = 0; mt < MT; ++mt) {
              const bf16x4 a = *reinterpret_cast<const bf16x4*>(
                  &sW2b[(16 * mt + m) * KS + 16 * kt + 4 * g]);
              acc[mt][0] = mfma16(a, sf[kt][0], acc[mt][0]);
              acc[mt][1] = mfma16(a, sf[kt][1], acc[mt][1]);
            }
          }

          // g2 = cos(h2+b2)*w3 ; lands directly in pass-2 B-frag layout (reuse sf)
          #pragma unroll
          for (int mt = 0; mt < MT; ++mt) {
            #pragma unroll
            for (int r = 0; r < 4; ++r) {
              const int j = 16 * mt + 4 * g + r;
              const float2 bw = sb2w3[j];
              sf[mt][0][r] = f2b(__cosf(acc[mt][0][r] + bw.x) * bw.y);
              sf[mt][1][r] = f2b(__cosf(acc[mt][1][r] + bw.x) * bw.y);
            }
          }

          // pass 2 (transposed): G1^T[k'][row] = W2^T @ G2^T (reuse acc)
          #pragma unroll
          for (int mt = 0; mt < MT; ++mt) { acc[mt][0] = (f32x4)0.f; acc[mt][1] = (f32x4)0.f; }
          #pragma unroll
          for (int kt = 0; kt < MT; ++kt) {
            #pragma unroll
            for (int mt = 0; mt < MT; ++mt) {
              const bf16x4 a = *reinterpret_cast<const bf16x4*>(
                  &sW2T[(16 * mt + m) * KS + 16 * kt + 4 * g]);
              acc[mt][0] = mfma16(a, sf[kt][0], acc[mt][0]);
              acc[mt][1] = mfma16(a, sf[kt][1], acc[mt][1]);
            }
          }

          // delta[row][c] = sum_k G1*cos(h1)*W1[k][c]; reduce over lane-groups
          float pc00 = 0.f, pc01 = 0.f, pc10 = 0.f, pc11 = 0.f;
          #pragma unroll
          for (int mt = 0; mt < MT; ++mt) {
            #pragma unroll
            for (int r = 0; r < 4; ++r) {
              const int k = 16 * mt + 4 * g + r;
              const float4 w = sW1b[k];
              const float e0v = acc[mt][0][r] * cosr[mt][0][r];
              const float e1v = acc[mt][1][r] * cosr[mt][1][r];
              pc00 = __builtin_fmaf(e0v, w.x, pc00);
              pc01 = __builtin_fmaf(e0v, w.y, pc01);
              pc10 = __builtin_fmaf(e1v, w.x, pc10);
              pc11 = __builtin_fmaf(e1v, w.y, pc11);
            }
          }
          pc00 += __shfl_xor(pc00, 16); pc00 += __shfl_xor(pc00, 32);
          pc01 += __shfl_xor(pc01, 16); pc01 += __shfl_xor(pc01, 32);
          pc10 += __shfl_xor(pc10, 16); pc10 += __shfl_xor(pc10, 32);
          pc11 += __shfl_xor(pc11, 16); pc11 += __shfl_xor(pc11, 32);

          if (e == 0) { dsav00 = pc00; dsav01 = pc01; dsav10 = pc10; dsav11 = pc11; }
          else {
            df00 = dsav00 - pc00; df01 = dsav01 - pc01;
            df10 = dsav10 - pc10; df11 = dsav11 - pc11;
          }
        } // e

        // state update: lane-group 0 -> rows [waveRow..+15], group 1 -> [+16..+31]
        if (g < 2) {
            const float d0 = (g == 0) ? df00 : df10;
            const float d1 = (g == 0) ? df01 : df11;
            const int row  = waveRow + ((g == 1) ? 16 : 0) + m;
            float* sp = reinterpret_cast<float*>(&sState[row]);
            if (pot == 0) { sp[2] -= d0; sp[3] -= d1; }
            else          { sp[0] += d0; sp[1] += d1; }
        }
      } // pot
    } // layer

    __syncthreads();
    if (tid < RB) {
        reinterpret_cast<float4*>(out)[gbase + tid] = sState[tid];
    }
}

extern "C" void kernel_launch(void* const* d_in, const int* in_sizes, int n_in,
                              void* d_out, int out_size, void* d_ws, size_t ws_size,
                              hipStream_t stream) {
    const float* z   = (const float*)d_in[0];
    const float* t   = (const float*)d_in[1];
    const float* Wq1 = (const float*)d_in[2];
    const float* bq1 = (const float*)d_in[3];
    const float* Wq2 = (const float*)d_in[4];
    const float* bq2 = (const float*)d_in[5];
    const float* wq3 = (const float*)d_in[6];
    const float* Wp1 = (const float*)d_in[7];
    const float* bp1 = (const float*)d_in[8];
    const float* Wp2 = (const float*)d_in[9];
    const float* bp2 = (const float*)d_in[10];
    const float* wp3 = (const float*)d_in[11];
    float* out = (float*)d_out;

    const int B = in_sizes[1];          // 131072 rows
    const int blocks = B / RB;          // 1024 blocks

    sympnet_kernel<<<blocks, 256, 0, stream>>>(
        z, t, Wq1, bq1, Wq2, bq2, wq3, Wp1, bp1, Wp2, bp2, wp3, out);
}

// Round 5
// 1182.435 us; speedup vs baseline: 3.2966x; 1.1352x over previous
//
#include <hip/hip_runtime.h>
#include <hip/hip_bf16.h>

#define HH 100      // hidden size
#define HP 112      // padded hidden (7*16)
#define MT 7        // 16-wide tiles over hidden
#define KS 120      // row stride (bf16 elems) of LDS W2 buffers
#define RB 128      // rows per block (4 waves * 32 rows)
#define LL 3

typedef __attribute__((ext_vector_type(4))) short bf16x4;
typedef __attribute__((ext_vector_type(4))) float f32x4;

// D = A(16x16) @ B(16x16) + C via v_mfma_f32_16x16x16_bf16 (gfx950).
// A: lane m=l&15 holds k=(l>>4)*4+i ; B: lane n=l&15 holds k=(l>>4)*4+i ;
// C/D: col=l&15, row=(l>>4)*4+reg.  Intrinsic (not asm) so the compiler
// inserts MFMA<->VALU hazard wait-states (R3's NaN).
__device__ __forceinline__ f32x4 mfma16(bf16x4 a, bf16x4 b, f32x4 c) {
#if __has_builtin(__builtin_amdgcn_mfma_f32_16x16x16bf16_1k)
    return __builtin_amdgcn_mfma_f32_16x16x16bf16_1k(a, b, c, 0, 0, 0);
#else
    asm volatile("s_nop 1\n\t"
                 "v_mfma_f32_16x16x16_bf16 %0, %1, %2, %0\n\t"
                 "s_nop 7\n\t"
                 "s_nop 7"
                 : "+v"(c) : "v"(a), "v"(b));
    return c;
#endif
}

__device__ __forceinline__ short f2b(float f) {
    union { __hip_bfloat16 h; short s; } u;
    u.h = __float2bfloat16(f);
    return u.s;
}

__global__ __launch_bounds__(256, 2) void sympnet_kernel(
    const float* __restrict__ z,   const float* __restrict__ t,
    const float* __restrict__ Wq1, const float* __restrict__ bq1,
    const float* __restrict__ Wq2, const float* __restrict__ bq2,
    const float* __restrict__ wq3,
    const float* __restrict__ Wp1, const float* __restrict__ bp1,
    const float* __restrict__ Wp2, const float* __restrict__ bp2,
    const float* __restrict__ wp3,
    float* __restrict__ out)
{
    __shared__ short  sW2b[HP * KS];   // W2[j][k] bf16, zero-padded
    __shared__ short  sW2T[HP * KS];   // W2^T[k'][j] bf16, zero-padded
    __shared__ float4 sW1b[HP];        // (W1[k][0],W1[k][1],W1[k][2],b1[k]), zero-padded
    __shared__ float2 sb2w3[HP];       // (b2[j], w3[j]), zero-padded
    __shared__ float4 sState[RB];      // (q0,q1,p0,p1) per row
    __shared__ float  sT[RB];

    const int tid = threadIdx.x;
    const int m   = tid & 15;          // lane & 15
    const int g   = (tid >> 4) & 3;    // lane-group within wave
    const int waveRow = (tid >> 6) * 32;
    const int gbase   = blockIdx.x * RB;

    if (tid < RB) {
        sState[tid] = reinterpret_cast<const float4*>(z)[gbase + tid];
        sT[tid]     = t[gbase + tid];
    }

    #pragma unroll 1
    for (int layer = 0; layer < LL; ++layer) {
      #pragma unroll 1
      for (int pot = 0; pot < 2; ++pot) {
        const float* gW2 = (pot ? Wp2 : Wq2) + layer * (HH * HH);
        const float* gW1 = (pot ? Wp1 : Wq1) + layer * (HH * 3);
        const float* gb1 = (pot ? bp1 : bq1) + layer * HH;
        const float* gb2 = (pot ? bp2 : bq2) + layer * HH;
        const float* gw3 = (pot ? wp3 : wq3) + layer * HH;

        __syncthreads();   // prior stage done with weight buffers (also covers init)

        // ---- stage sW2b (coalesced) + small weights ----
        #pragma unroll 1
        for (int idx = tid; idx < HP * 30; idx += 256) {
            const int j  = idx / 30;
            const int kc = idx - j * 30;
            bf16x4 v = {0, 0, 0, 0};
            if (j < HH && kc < 25) {
                const float4 w = reinterpret_cast<const float4*>(gW2)[j * 25 + kc];
                v[0] = f2b(w.x); v[1] = f2b(w.y); v[2] = f2b(w.z); v[3] = f2b(w.w);
            }
            *reinterpret_cast<bf16x4*>(&sW2b[j * KS + 4 * kc]) = v;
        }
        if (tid < HP) {
            float4 w  = make_float4(0.f, 0.f, 0.f, 0.f);
            float2 bw = make_float2(0.f, 0.f);
            if (tid < HH) {
                w  = make_float4(gW1[tid * 3], gW1[tid * 3 + 1], gW1[tid * 3 + 2], gb1[tid]);
                bw = make_float2(gb2[tid], gw3[tid]);
            }
            sW1b[tid]  = w;
            sb2w3[tid] = bw;
        }
        __syncthreads();

        // ---- transpose sW2b -> sW2T in LDS ----
        #pragma unroll 1
        for (int idx = tid; idx < HP * 30; idx += 256) {
            const int kp = idx % HP;
            const int jc = idx / HP;        // 0..29
            bf16x4 v;
            #pragma unroll
            for (int i = 0; i < 4; ++i) {
                const int j = 4 * jc + i;
                v[i] = (j < HP) ? sW2b[j * KS + kp] : (short)0;
            }
            *reinterpret_cast<bf16x4*>(&sW2T[kp * KS + 4 * jc]) = v;
        }
        __syncthreads();

        // ---- compute: wave owns 32 rows (two 16-row tiles) ----
        const float4 s0 = sState[waveRow + m];
        const float4 s1 = sState[waveRow + 16 + m];
        const float tr0 = sT[waveRow + m];
        const float tr1 = sT[waveRow + 16 + m];
        const float x00 = pot ? s0.z : s0.x, x01 = pot ? s0.w : s0.y;
        const float x10 = pot ? s1.z : s1.x, x11 = pot ? s1.w : s1.y;

        float dsav00 = 0.f, dsav01 = 0.f, dsav10 = 0.f, dsav11 = 0.f;
        float df00 = 0.f, df01 = 0.f, df10 = 0.f, df11 = 0.f;

        #pragma unroll 1
        for (int e = 0; e < 2; ++e) {
          const float xt0 = e ? 0.f : tr0;
          const float xt1 = e ? 0.f : tr1;

          // ---- stage 1: sin(h1) straight into pass-1 B-frag layout.
          // NOTE: no cos cache (R4 spilled 56 VGPRs) — cos(h1) is recomputed
          // in the epilogue from sW1b, which it reads anyway.
          bf16x4 sf[MT][2];
          #pragma unroll
          for (int mt = 0; mt < MT; ++mt) {
            #pragma unroll
            for (int r = 0; r < 4; ++r) {
              const int k = 16 * mt + 4 * g + r;
              const float4 w = sW1b[k];
              const float h0 = __builtin_fmaf(w.x, x00,
                               __builtin_fmaf(w.y, x01,
                               __builtin_fmaf(w.z, xt0, w.w)));
              const float h1 = __builtin_fmaf(w.x, x10,
                               __builtin_fmaf(w.y, x11,
                               __builtin_fmaf(w.z, xt1, w.w)));
              sf[mt][0][r] = f2b(__sinf(h0));
              sf[mt][1][r] = f2b(__sinf(h1));
            }
          }

          // pass 1 (transposed): H2^T[j][row] = W2 @ S1^T
          f32x4 acc[MT][2];
          #pragma unroll
          for (int mt = 0; mt < MT; ++mt) { acc[mt][0] = (f32x4)0.f; acc[mt][1] = (f32x4)0.f; }
          #pragma unroll
          for (int kt = 0; kt < MT; ++kt) {
            #pragma unroll
            for (int mt = 0; mt < MT; ++mt) {
              const bf16x4 a = *reinterpret_cast<const bf16x4*>(
                  &sW2b[(16 * mt + m) * KS + 16 * kt + 4 * g]);
              acc[mt][0] = mfma16(a, sf[kt][0], acc[mt][0]);
              acc[mt][1] = mfma16(a, sf[kt][1], acc[mt][1]);
            }
          }

          // g2 = cos(h2+b2)*w3 ; lands directly in pass-2 B-frag layout (reuse sf)
          #pragma unroll
          for (int mt = 0; mt < MT; ++mt) {
            #pragma unroll
            for (int r = 0; r < 4; ++r) {
              const int j = 16 * mt + 4 * g + r;
              const float2 bw = sb2w3[j];
              sf[mt][0][r] = f2b(__cosf(acc[mt][0][r] + bw.x) * bw.y);
              sf[mt][1][r] = f2b(__cosf(acc[mt][1][r] + bw.x) * bw.y);
            }
          }

          // pass 2 (transposed): G1^T[k'][row] = W2^T @ G2^T (reuse acc)
          #pragma unroll
          for (int mt = 0; mt < MT; ++mt) { acc[mt][0] = (f32x4)0.f; acc[mt][1] = (f32x4)0.f; }
          #pragma unroll
          for (int kt = 0; kt < MT; ++kt) {
            #pragma unroll
            for (int mt = 0; mt < MT; ++mt) {
              const bf16x4 a = *reinterpret_cast<const bf16x4*>(
                  &sW2T[(16 * mt + m) * KS + 16 * kt + 4 * g]);
              acc[mt][0] = mfma16(a, sf[kt][0], acc[mt][0]);
              acc[mt][1] = mfma16(a, sf[kt][1], acc[mt][1]);
            }
          }

          // epilogue: recompute h1/cos(h1); delta[row][c] = sum_k G1*cos*W1[k][c]
          float pc00 = 0.f, pc01 = 0.f, pc10 = 0.f, pc11 = 0.f;
          #pragma unroll
          for (int mt = 0; mt < MT; ++mt) {
            #pragma unroll
            for (int r = 0; r < 4; ++r) {
              const int k = 16 * mt + 4 * g + r;
              const float4 w = sW1b[k];
              const float h0 = __builtin_fmaf(w.x, x00,
                               __builtin_fmaf(w.y, x01,
                               __builtin_fmaf(w.z, xt0, w.w)));
              const float h1 = __builtin_fmaf(w.x, x10,
                               __builtin_fmaf(w.y, x11,
                               __builtin_fmaf(w.z, xt1, w.w)));
              const float e0v = acc[mt][0][r] * __cosf(h0);
              const float e1v = acc[mt][1][r] * __cosf(h1);
              pc00 = __builtin_fmaf(e0v, w.x, pc00);
              pc01 = __builtin_fmaf(e0v, w.y, pc01);
              pc10 = __builtin_fmaf(e1v, w.x, pc10);
              pc11 = __builtin_fmaf(e1v, w.y, pc11);
            }
          }
          pc00 += __shfl_xor(pc00, 16); pc00 += __shfl_xor(pc00, 32);
          pc01 += __shfl_xor(pc01, 16); pc01 += __shfl_xor(pc01, 32);
          pc10 += __shfl_xor(pc10, 16); pc10 += __shfl_xor(pc10, 32);
          pc11 += __shfl_xor(pc11, 16); pc11 += __shfl_xor(pc11, 32);

          if (e == 0) { dsav00 = pc00; dsav01 = pc01; dsav10 = pc10; dsav11 = pc11; }
          else {
            df00 = dsav00 - pc00; df01 = dsav01 - pc01;
            df10 = dsav10 - pc10; df11 = dsav11 - pc11;
          }
        } // e

        // state update: lane-group 0 -> rows [waveRow..+15], group 1 -> [+16..+31]
        if (g < 2) {
            const float d0 = (g == 0) ? df00 : df10;
            const float d1 = (g == 0) ? df01 : df11;
            const int row  = waveRow + ((g == 1) ? 16 : 0) + m;
            float* sp = reinterpret_cast<float*>(&sState[row]);
            if (pot == 0) { sp[2] -= d0; sp[3] -= d1; }
            else          { sp[0] += d0; sp[1] += d1; }
        }
      } // pot
    } // layer

    __syncthreads();
    if (tid < RB) {
        reinterpret_cast<float4*>(out)[gbase + tid] = sState[tid];
    }
}

extern "C" void kernel_launch(void* const* d_in, const int* in_sizes, int n_in,
                              void* d_out, int out_size, void* d_ws, size_t ws_size,
                              hipStream_t stream) {
    const float* z   = (const float*)d_in[0];
    const float* t   = (const float*)d_in[1];
    const float* Wq1 = (const float*)d_in[2];
    const float* bq1 = (const float*)d_in[3];
    const float* Wq2 = (const float*)d_in[4];
    const float* bq2 = (const float*)d_in[5];
    const float* wq3 = (const float*)d_in[6];
    const float* Wp1 = (const float*)d_in[7];
    const float* bp1 = (const float*)d_in[8];
    const float* Wp2 = (const float*)d_in[9];
    const float* bp2 = (const float*)d_in[10];
    const float* wp3 = (const float*)d_in[11];
    float* out = (float*)d_out;

    const int B = in_sizes[1];          // 131072 rows
    const int blocks = B / RB;          // 1024 blocks

    sympnet_kernel<<<blocks, 256, 0, stream>>>(
        z, t, Wq1, bq1, Wq2, bq2, wq3, Wp1, bp1, Wp2, bp2, wp3, out);
}